// Round 6
// baseline (983.712 us; speedup 1.0000x reference)
//
#include <hip/hip_runtime.h>
#include <hip/hip_bf16.h>
#include <hip/hip_cooperative_groups.h>

namespace cg = cooperative_groups;

// Problem constants (fixed by the reference):
#define E_EDGES 640000
#define DIM     128
#define N_NODES 40000

// Atomic-free cooperative counting sort parameters.
#define NB     625          // sort blocks; 625 * 1024 = E exactly
#define NBIN1  157          // coarse buckets: ceil(40000/256); digit1 = k>>8

// Fallback (R5) replicated-histogram parameters.
#define KREP  16
#define HSIZE (KREP * N_NODES)

typedef __bf16 bf16x8 __attribute__((ext_vector_type(8)));
typedef float  floatx4 __attribute__((ext_vector_type(4)));

// ---------------------------------------------------------------------------
// W swizzle into bf16 B-fragment lane order:
// Wsw[((nb*4+kb)*64 + lane)*8 + j] = W[nb*16 + (lane&15)][kb*32 + (lane>>4)*8 + j]
// ---------------------------------------------------------------------------
__device__ __forceinline__ void swizzle_w(const float* __restrict__ W,
                                          __bf16* __restrict__ Wsw, int tid) {
    int lane = tid & 63;
    int kb   = (tid >> 6) & 3;
    int nb   = tid >> 8;
    int f    = nb * 16 + (lane & 15);
    int k0   = kb * 32 + ((lane >> 4) & 3) * 8;
    const float* wrow = W + f * DIM + k0;
    __bf16* o = Wsw + tid * 8;
#pragma unroll
    for (int j = 0; j < 8; ++j) o[j] = (__bf16)wrow[j];
}

// ---------------------------------------------------------------------------
// sort_all: ONE cooperative kernel, ZERO global atomics.
//   P0 : pairs buf0[i] = (dst[i], i); W swizzle
//   P1A: per-block LDS hist of digit1 (k>>8, 157 bins) -> Hg[d][b]
//   P1B: blocks 0..156: exclusive scan Hg[d][*] over blocks (in place) + total[d]
//   P1C: block 0: exclusive scan total -> base[d]; base[157] = E
//   P1D: scatter pairs into coarse buckets (LDS cursor; plain global stores)
//   P2 : blocks 0..156: bucket-local sort by digit0 via LDS hist+scan+cursor
//        (MSB-first => stability NOT required; max-reduce is order-invariant)
//   P3 : perm extraction + lower-bound boundaries starts[0..N]
// ---------------------------------------------------------------------------
__global__ __launch_bounds__(256)
void sort_all(const float* __restrict__ W, const int* __restrict__ dst,
              __bf16* __restrict__ Wsw,
              int2* __restrict__ buf0, int2* __restrict__ buf1,
              int* __restrict__ Hg, int* __restrict__ total,
              int* __restrict__ base, int* __restrict__ perm,
              int* __restrict__ starts) {
    cg::grid_group grid = cg::this_grid();
    __shared__ int h[256];
    __shared__ int c[256];
    const int t   = threadIdx.x;
    const int b   = blockIdx.x;
    const int tid = b * 256 + t;

    // ---- P0 ----
    for (int i = tid; i < E_EDGES; i += NB * 256)
        buf0[i] = make_int2(dst[i], i);
    if (tid < 2048) swizzle_w(W, Wsw, tid);
    grid.sync();

    // ---- P1A ----
    if (t < NBIN1) h[t] = 0;
    __syncthreads();
    {
        const int lo = b * 1024;
#pragma unroll
        for (int r = 0; r < 4; ++r)
            atomicAdd(&h[buf0[lo + r * 256 + t].x >> 8], 1);   // LDS atomic
    }
    __syncthreads();
    if (t < NBIN1) Hg[t * NB + b] = h[t];
    grid.sync();

    // ---- P1B ---- (block d scans Hg[d][0..624] -> exclusive, total[d])
    if (b < NBIN1) {
        int i0 = t * 3;
        int v0 = 0, v1 = 0, v2 = 0, s = 0;
        if (i0     < NB) { v0 = Hg[b * NB + i0];     s += v0; }
        if (i0 + 1 < NB) { v1 = Hg[b * NB + i0 + 1]; s += v1; }
        if (i0 + 2 < NB) { v2 = Hg[b * NB + i0 + 2]; s += v2; }
        h[t] = s;
        __syncthreads();
        for (int off = 1; off < 256; off <<= 1) {
            int u = (t >= off) ? h[t - off] : 0;
            __syncthreads();
            h[t] += u;
            __syncthreads();
        }
        int run = h[t] - s;
        if (i0     < NB) { Hg[b * NB + i0]     = run; run += v0; }
        if (i0 + 1 < NB) { Hg[b * NB + i0 + 1] = run; run += v1; }
        if (i0 + 2 < NB) { Hg[b * NB + i0 + 2] = run; run += v2; }
        if (t == 255) total[b] = h[255];
    }
    grid.sync();

    // ---- P1C ----
    if (b == 0) {
        int v = (t < NBIN1) ? total[t] : 0;
        int orig = v;
        h[t] = v;
        __syncthreads();
        for (int off = 1; off < 256; off <<= 1) {
            int u = (t >= off) ? h[t - off] : 0;
            __syncthreads();
            h[t] += u;
            __syncthreads();
        }
        if (t < NBIN1) base[t] = h[t] - orig;
        if (t == 0) base[NBIN1] = E_EDGES;
    }
    grid.sync();

    // ---- P1D ----
    if (t < NBIN1) c[t] = Hg[t * NB + b];
    __syncthreads();
    {
        const int lo = b * 1024;
#pragma unroll
        for (int r = 0; r < 4; ++r) {
            int2 p = buf0[lo + r * 256 + t];
            int d = p.x >> 8;
            int pos = base[d] + atomicAdd(&c[d], 1);   // LDS atomic cursor
            buf1[pos] = p;                              // plain global store
        }
    }
    grid.sync();

    // ---- P2 ---- (bucket-local sort by low 8 bits)
    if (b < NBIN1) {
        const int lo = base[b], hi = base[b + 1];
        h[t] = 0;
        __syncthreads();
        for (int i = lo + t; i < hi; i += 256)
            atomicAdd(&h[buf1[i].x & 255], 1);          // LDS atomic
        __syncthreads();
        int orig = h[t];
        for (int off = 1; off < 256; off <<= 1) {
            int u = (t >= off) ? h[t - off] : 0;
            __syncthreads();
            h[t] += u;
            __syncthreads();
        }
        c[t] = h[t] - orig;                              // exclusive
        __syncthreads();
        for (int i = lo + t; i < hi; i += 256) {
            int2 p = buf1[i];
            int pos = lo + atomicAdd(&c[p.x & 255], 1);  // LDS atomic cursor
            buf0[pos] = p;                               // plain global store
        }
    }
    grid.sync();

    // ---- P3 ---- perm + lower-bound boundaries (starts[n] = first i, key>=n)
    for (int i = tid; i < E_EDGES; i += NB * 256) {
        int2 p = buf0[i];
        perm[i] = p.y;
        int k  = p.x;
        int kp = (i == 0) ? -1 : buf0[i - 1].x;
        for (int n = kp + 1; n <= k; ++n) starts[n] = i;
        if (i == E_EDGES - 1)
            for (int n = k + 1; n <= N_NODES; ++n) starts[n] = E_EDGES;
    }
}

// --------------------- fallback prep kernels (R5 path) ---------------------
__global__ void prep0_kernel(const float* __restrict__ W,
                             __bf16* __restrict__ Wsw,
                             int* __restrict__ H) {
    int tid = blockIdx.x * 256 + threadIdx.x;
    if (tid < HSIZE) H[tid] = 0;
    if (tid < 2048) swizzle_w(W, Wsw, tid);
}
__global__ void hist16_kernel(const int* __restrict__ dst, int* __restrict__ H) {
    int e = blockIdx.x * 256 + threadIdx.x;
    atomicAdd(&H[(e & (KREP - 1)) * N_NODES + dst[e]], 1);
}
__global__ __launch_bounds__(256)
void sum_kernel(const int* __restrict__ H, int* __restrict__ cnt,
                int* __restrict__ bsum) {
    __shared__ int sred[256];
    int n = blockIdx.x * 256 + threadIdx.x;
    int s = 0;
    if (n < N_NODES) {
#pragma unroll
        for (int r = 0; r < KREP; ++r) s += H[r * N_NODES + n];
        cnt[n] = s;
    }
    sred[threadIdx.x] = s;
    __syncthreads();
    for (int off = 128; off > 0; off >>= 1) {
        if (threadIdx.x < off) sred[threadIdx.x] += sred[threadIdx.x + off];
        __syncthreads();
    }
    if (threadIdx.x == 0) bsum[blockIdx.x] = sred[0];
}
__global__ __launch_bounds__(256)
void scanb_kernel(const int* __restrict__ bsum, int* __restrict__ bstart) {
    __shared__ int ss[256];
    int t = threadIdx.x;
    int v = (t < 160) ? bsum[t] : 0;
    int orig = v;
    ss[t] = v;
    __syncthreads();
    for (int off = 1; off < 256; off <<= 1) {
        int u = (t >= off) ? ss[t - off] : 0;
        __syncthreads();
        ss[t] += u;
        __syncthreads();
    }
    if (t < 160) bstart[t] = ss[t] - orig;
}
__global__ __launch_bounds__(256)
void offs_kernel(int* __restrict__ H, const int* __restrict__ cnt,
                 const int* __restrict__ bstart, int* __restrict__ starts) {
    __shared__ int ss[256];
    int t = threadIdx.x;
    int n = blockIdx.x * 256 + t;
    int v = (n < N_NODES) ? cnt[n] : 0;
    int orig = v;
    ss[t] = v;
    __syncthreads();
    for (int off = 1; off < 256; off <<= 1) {
        int u = (t >= off) ? ss[t - off] : 0;
        __syncthreads();
        ss[t] += u;
        __syncthreads();
    }
    if (n < N_NODES) {
        int run = bstart[blockIdx.x] + ss[t] - orig;
        starts[n] = run;
#pragma unroll
        for (int r = 0; r < KREP; ++r) {
            int idx = r * N_NODES + n;
            int h = H[idx];
            H[idx] = run;
            run += h;
        }
    }
}
__global__ void scatter16_kernel(const int* __restrict__ dst,
                                 int* __restrict__ H, int* __restrict__ perm) {
    int e = blockIdx.x * 256 + threadIdx.x;
    int pos = atomicAdd(&H[(e & (KREP - 1)) * N_NODES + dst[e]], 1);
    perm[pos] = e;
}

// ---------------------------------------------------------------------------
// Main gemm kernel. One wave per node per group-iteration; W staged in LDS
// ONCE per block, then ngroups node-iterations amortize the staging/barrier
// (R5 churn fix: 10000 short blocks -> 2500 blocks x 4 nodes/wave).
// st_mode: 2 -> cnt = starts+1, stends = starts (c = s1-s0, st = s0)
//          0 -> c = cnt[node], st = stends[node] (unbumped starts)
//          1 -> c = cnt[node], st = stends[node] - c (bumped starts)
// A-frag:  A[m=lane&15][k=q*8+j]   (gathered rows, 16B loads)
// B-frag:  B[k=q*8+j][n=lane&15]   (pre-swizzled, staged in LDS per block)
// C/D:     col=lane&15, row=q*4+reg
// ---------------------------------------------------------------------------
__global__ __launch_bounds__(256)
void node_gemm_kernel(const float* __restrict__ src,
                      const __bf16* __restrict__ Wsw,
                      const float* __restrict__ bias,
                      const int* __restrict__ perm,
                      const int* __restrict__ cnt,
                      const int* __restrict__ stends,
                      float* __restrict__ out, int st_mode, int ngroups) {
    __shared__ bf16x8 Wl[2048];   // 32 KB swizzled W, shared by 4 waves
    const int t = threadIdx.x;
    {
        const float4* gw = (const float4*)Wsw;
        float4* lw = (float4*)Wl;
#pragma unroll
        for (int i = 0; i < 8; ++i) lw[t + i * 256] = gw[t + i * 256];
    }
    __syncthreads();

    const int lane = t & 63;
    const int wave = t >> 6;
    const int q    = lane >> 4;
    const int n    = lane & 15;

    for (int g = 0; g < ngroups; ++g) {
        const int node = (blockIdx.x + g * gridDim.x) * 4 + wave;
        if (node >= N_NODES) break;

        const int cv = cnt[node];
        const int se = stends[node];
        int c, st;
        if (st_mode == 2)      { c = cv - se; st = se; }
        else if (st_mode == 1) { c = cv; st = se - cv; }
        else                   { c = cv; st = se; }

        float* orow = out + (size_t)node * DIM;

        if (c == 0) {   // empty segment: -inf, matching jax segment_max
            orow[lane]      = -INFINITY;
            orow[lane + 64] = -INFINITY;
            continue;
        }

        floatx4 vmax[8];
#pragma unroll
        for (int nb = 0; nb < 8; ++nb) vmax[nb] = (floatx4)(-INFINITY);

        const int nch = (c + 15) >> 4;
        for (int ch = 0; ch < nch; ++ch) {
            int rows = c - (ch << 4);
            if (rows > 16) rows = 16;
            int e = (n < rows) ? perm[st + (ch << 4) + n] : 0;
            const float* arow = src + (size_t)e * DIM + q * 8;

            floatx4 acc[8];
#pragma unroll
            for (int nb = 0; nb < 8; ++nb) acc[nb] = (floatx4)(0.0f);

#pragma unroll
            for (int kb = 0; kb < 4; ++kb) {
                float4 a0 = *(const float4*)(arow + kb * 32);
                float4 a1 = *(const float4*)(arow + kb * 32 + 4);
                bf16x8 af;
                af[0] = (__bf16)a0.x; af[1] = (__bf16)a0.y;
                af[2] = (__bf16)a0.z; af[3] = (__bf16)a0.w;
                af[4] = (__bf16)a1.x; af[5] = (__bf16)a1.y;
                af[6] = (__bf16)a1.z; af[7] = (__bf16)a1.w;
#pragma unroll
                for (int nb = 0; nb < 8; ++nb) {
                    bf16x8 bf = Wl[(nb * 4 + kb) * 64 + lane];
                    acc[nb] = __builtin_amdgcn_mfma_f32_16x16x32_bf16(af, bf, acc[nb], 0, 0, 0);
                }
            }

#pragma unroll
            for (int nb = 0; nb < 8; ++nb)
#pragma unroll
                for (int r = 0; r < 4; ++r) {
                    float v = (q * 4 + r < rows) ? acc[nb][r] : -INFINITY;
                    vmax[nb][r] = fmaxf(vmax[nb][r], v);
                }
        }

        float red[8];
#pragma unroll
        for (int nb = 0; nb < 8; ++nb) {
            float v = fmaxf(fmaxf(vmax[nb][0], vmax[nb][1]),
                            fmaxf(vmax[nb][2], vmax[nb][3]));
            v = fmaxf(v, __shfl_xor(v, 16));
            v = fmaxf(v, __shfl_xor(v, 32));
            red[nb] = v;
        }
        float o1 = (q == 0) ? red[0] : (q == 1) ? red[1] : (q == 2) ? red[2] : red[3];
        float o2 = (q == 0) ? red[4] : (q == 1) ? red[5] : (q == 2) ? red[6] : red[7];
        // bias-add and relu commute with max (bias per-column, relu monotone)
        orow[lane]      = fmaxf(o1 + bias[lane],      0.0f);
        orow[lane + 64] = fmaxf(o2 + bias[lane + 64], 0.0f);
    }
}

extern "C" void kernel_launch(void* const* d_in, const int* in_sizes, int n_in,
                              void* d_out, int out_size, void* d_ws, size_t ws_size,
                              hipStream_t stream) {
    const float* src  = (const float*)d_in[0];
    const float* W    = (const float*)d_in[1];
    const float* bias = (const float*)d_in[2];
    const int*   dst  = (const int*)d_in[3];
    // d_in[4] = n_nodes (scalar) — compile-time constant here.

    float* outf = (float*)d_out;
    char* ws = (char*)d_ws;

    // ---- coop layout (~12.8 MB) ----
    size_t off = 0;
    __bf16* Wsw  = (__bf16*)(ws + off); off += 32768;
    int* starts  = (int*)(ws + off);    off += 160016;        // N+1 ints, padded
    int* perm    = (int*)(ws + off);    off += 2560000;
    int2* buf0   = (int2*)(ws + off);   off += 5120000;
    int2* buf1   = (int2*)(ws + off);   off += 5120000;
    int* Hg      = (int*)(ws + off);    off += 392512;        // 157*625 ints
    int* total   = (int*)(ws + off);    off += 640;
    int* base    = (int*)(ws + off);    off += 640;
    const size_t coop_need = off;

    bool done = false;
    if (ws_size >= coop_need) {
        void* kargs[] = {(void*)&W, (void*)&dst, (void*)&Wsw, (void*)&buf0,
                         (void*)&buf1, (void*)&Hg, (void*)&total, (void*)&base,
                         (void*)&perm, (void*)&starts};
        hipError_t cerr = hipLaunchCooperativeKernel((const void*)sort_all,
                                                     dim3(NB), dim3(256),
                                                     kargs, 0, stream);
        if (cerr == hipSuccess) {
            node_gemm_kernel<<<2500, 256, 0, stream>>>(
                src, Wsw, bias, perm, starts + 1, starts, outf, 2, 4);
            done = true;
        } else {
            (void)hipGetLastError();   // clear sticky error; fall through
        }
    }

    if (!done) {
        // ---- fallback: R5 replicated-histogram path (measured-correct) ----
        size_t f = 0;
        __bf16* fWsw = (__bf16*)(ws + f); f += 32768;
        int* cnt     = (int*)(ws + f);    f += 160000;
        int* fstarts = (int*)(ws + f);    f += 160000;
        int* fperm   = (int*)(ws + f);    f += 2560000;
        int* bsum    = (int*)(ws + f);    f += 1024;
        int* bstart  = (int*)(ws + f);    f += 1024;
        int* H       = (int*)(ws + f);    f += (size_t)HSIZE * 4;
        prep0_kernel<<<2500, 256, 0, stream>>>(W, fWsw, H);
        hist16_kernel<<<E_EDGES / 256, 256, 0, stream>>>(dst, H);
        sum_kernel<<<160, 256, 0, stream>>>(H, cnt, bsum);
        scanb_kernel<<<1, 256, 0, stream>>>(bsum, bstart);
        offs_kernel<<<160, 256, 0, stream>>>(H, cnt, bstart, fstarts);
        scatter16_kernel<<<E_EDGES / 256, 256, 0, stream>>>(dst, H, fperm);
        node_gemm_kernel<<<10000, 256, 0, stream>>>(
            src, fWsw, bias, fperm, cnt, fstarts, outf, 0, 1);
    }
}